// Round 5
// baseline (529.650 us; speedup 1.0000x reference)
//
#include <hip/hip_runtime.h>
#include <hip/hip_bf16.h>
#include <cstdio>

// ---------------------------------------------------------------------------
// Attn_59940563583594: hidden[32,1024,768] -> QKV -> causal attn (no 1/sqrt(d))
//                      -> relu MLP(768->64) -> out[32,1024,2] fp32
// Numerics (verified R2-R8: absmax 9.8e-4 vs 3.8e-3 threshold):
//   f16 storage/MFMA for hidden/W/q/k, no-max softmax (exp clamp 80,
//   unnormalized bf16 p, fp32 row sums, normalize in PV), bf16 PV + MLP.
// R11-R13: 256^2 8-phase schedule stuck at 678 TF == 2-phase ceiling; R13
//   (clobber removal) null -> per-phase drains persist. Quantitative fit:
//   ~1280 cyc stall/phase == one HBM-latency drain. Mechanism: LLVM's
//   LDS-DMA tracking inserts conservative vmcnt(0) before ds_reads that
//   may alias in-flight global_load_lds destinations (runtime dbuf index).
// R14: remove LDS-DMA entirely -> reg-staged pipeline (T14/HK):
//   global_load_dwordx4 -> named VGPR slots at the old issue points,
//   ds_write_b128 two phases later (2-phase latency cover, <=2 stages in
//   flight, 4 named slots). vmcnt now guards only reg loads (compiler
//   tracks precisely); each phase drains lgkmcnt(0) BEFORE its raw
//   s_barrier to publish ds_writes. Same phases/grids/epilogues/math.
// ---------------------------------------------------------------------------

typedef _Float16 f16;
typedef f16    f16x8 __attribute__((ext_vector_type(8)));
typedef f16    f16x4 __attribute__((ext_vector_type(4)));
typedef __bf16 bfx8  __attribute__((ext_vector_type(8)));
typedef float  f32x4 __attribute__((ext_vector_type(4)));
typedef unsigned int u32;
typedef u32    u32x4 __attribute__((ext_vector_type(4)));

#define MFMA_F16(a,b,c)  __builtin_amdgcn_mfma_f32_16x16x32_f16((a),(b),(c),0,0,0)
#define MFMA_BF16(a,b,c) __builtin_amdgcn_mfma_f32_16x16x32_bf16((a),(b),(c),0,0,0)

static constexpr int LDT2 = 264;  // qkv v-transpose stride (128e x 256s)

// publish LDS writes + finish own LDS reads, then pin (no vmem writes LDS
// anymore, so the memory clobber cannot trigger vmcnt drains)
#define PUB()                                                \
    do { asm volatile("s_waitcnt lgkmcnt(0)" ::: "memory");  \
         __builtin_amdgcn_sched_barrier(0); } while (0)

// ---------------- fp32 -> f16 convert (hidden + 3 weights, one dispatch) ----
__global__ __launch_bounds__(256) void cvt_all(
    const float* __restrict__ hidden,
    const float* __restrict__ Wq, const float* __restrict__ Wk, const float* __restrict__ Wv,
    f16* __restrict__ h16, f16* __restrict__ oq, f16* __restrict__ ok, f16* __restrict__ ov)
{
    const int bid = blockIdx.x;
    const float* src;
    f16* dst;
    int base;
    if (bid < 24576) {
        src = hidden; dst = h16;
        base = (bid * 256 + threadIdx.x) * 4;
    } else {
        int wz = (bid - 24576) / 576, wb = (bid - 24576) % 576;
        src = (wz == 0) ? Wq : (wz == 1) ? Wk : Wv;
        dst = (wz == 0) ? oq : (wz == 1) ? ok : ov;
        base = (wb * 256 + threadIdx.x) * 4;
    }
    f32x4 v = *(const f32x4*)(src + base);
    f16x4 o;
    #pragma unroll
    for (int e = 0; e < 4; ++e) o[e] = (f16)v[e];
    *(f16x4*)(dst + base) = o;
}

// ---- 8-phase QPHASE: {ds_read A-frags | ST prev slot | LD next slot |
//                       lgkm0 publish | barrier | 16 MFMA | barrier}
#define QPHASE(fr0, ST_STMT, LD_STMT)                                             \
    {                                                                             \
        f16x8 afr[2][2];                                                          \
        _Pragma("unroll")                                                         \
        for (int i = 0; i < 2; ++i) {                                             \
            _Pragma("unroll")                                                     \
            for (int kk2 = 0; kk2 < 2; ++kk2)                                     \
                afr[i][kk2] = *(const f16x8*)&SA[kk2 * 8192 + (wr8 + (fr0) + i) * 512 + lq]; \
        }                                                                         \
        ST_STMT;                                                                  \
        LD_STMT;                                                                  \
        PUB();                                                                    \
        __builtin_amdgcn_s_barrier();                                             \
        __builtin_amdgcn_s_setprio(1);                                            \
        _Pragma("unroll")                                                         \
        for (int i = 0; i < 2; ++i) {                                             \
            _Pragma("unroll")                                                     \
            for (int jj = 0; jj < 4; ++jj) {                                      \
                acc[(fr0) + i][jj] = MFMA_F16(afr[i][0], bfr[jj][0], acc[(fr0) + i][jj]); \
                acc[(fr0) + i][jj] = MFMA_F16(afr[i][1], bfr[jj][1], acc[(fr0) + i][jj]); \
            }                                                                     \
        }                                                                         \
        __builtin_amdgcn_s_setprio(0);                                            \
        __builtin_amdgcn_s_barrier();                                             \
    }

#define QPHASE_BF(fr0, ST_STMT, LD_STMT)                                          \
    {                                                                             \
        bfx8 afr[2][2];                                                           \
        _Pragma("unroll")                                                         \
        for (int i = 0; i < 2; ++i) {                                             \
            _Pragma("unroll")                                                     \
            for (int kk2 = 0; kk2 < 2; ++kk2)                                     \
                afr[i][kk2] = *(const bfx8*)&SA[kk2 * 8192 + (wr8 + (fr0) + i) * 512 + lq]; \
        }                                                                         \
        ST_STMT;                                                                  \
        LD_STMT;                                                                  \
        PUB();                                                                    \
        __builtin_amdgcn_s_barrier();                                             \
        __builtin_amdgcn_s_setprio(1);                                            \
        _Pragma("unroll")                                                         \
        for (int i = 0; i < 2; ++i) {                                             \
            _Pragma("unroll")                                                     \
            for (int jj = 0; jj < 4; ++jj) {                                      \
                acc[(fr0) + i][jj] = MFMA_BF16(afr[i][0], bfr[jj][0], acc[(fr0) + i][jj]); \
                acc[(fr0) + i][jj] = MFMA_BF16(afr[i][1], bfr[jj][1], acc[(fr0) + i][jj]); \
            }                                                                     \
        }                                                                         \
        __builtin_amdgcn_s_setprio(0);                                            \
        __builtin_amdgcn_s_barrier();                                             \
    }

// stage slot helpers (two 16B chunks per thread per stage)
#define LD2(s_a, s_b, GP)                                    \
    do { const char* _g = (const char*)(GP);                 \
         s_a = *(const u32x4*)_g;                            \
         s_b = *(const u32x4*)(_g + GO1B); } while (0)
#define ST2(s_a, s_b, LP)                                    \
    do { char* _l = (char*)(LP);                             \
         *(u32x4*)_l = s_a;                                  \
         *(u32x4*)(_l + 1024) = s_b; } while (0)

// ---------------- K1: fused q,k,v projections, 256x256 8-phase --------------
// grid 1152 = 8 xcd * (3 nt * 3 z * 16 mi); mt = xcd + 8*mi; 512 threads.
__global__ __launch_bounds__(512, 2) void qkv_kernel(
    const f16* __restrict__ h16,
    const f16* __restrict__ wq, const f16* __restrict__ wk, const f16* __restrict__ wv,
    const float* __restrict__ bq, const float* __restrict__ bk, const float* __restrict__ bv,
    f16* __restrict__ q16, f16* __restrict__ k16, __bf16* __restrict__ vT)
{
    const int f = blockIdx.x;
    const int xcd = f & 7;
    const int j = f >> 3;
    const int nt = j % 3;
    const int z  = (j / 3) % 3;
    const int mi = j / 9;                 // [0,16)
    const int mt = xcd + 8 * mi;          // [0,128)
    const int m0 = mt * 256, n0 = nt * 256;

    const f16* W = (z == 0) ? wq : (z == 1) ? wk : wv;
    const float* bias = (z == 0) ? bq : (z == 1) ? bk : bv;

    __shared__ alignas(16) f16 S[65536];  // 128 KB

    const int t = threadIdx.x, lane = t & 63, wave = t >> 6;
    const int wr = wave >> 2, wc = wave & 3;      // 2M x 4N wave grid
    const int wr8 = wr * 8;
    const int quad = lane >> 4, l16 = lane & 15;
    const int lq = quad * 128 + l16 * 8;

    enum { GO1B = 16 * 768 * 2, HOFF = 128 * 768 };
    const int c0 = (wave * 2) & 7, kk0 = wave >> 2;  // unit0 chunk / K-half
    const int gofs0 = c0 * 16 * 768 + kk0 * 32;
    const int lofs0 = kk0 * 8192 + c0 * 512 + lane * 8;

    const f16* gA = h16 + (size_t)(m0 + l16) * 768 + quad * 8 + gofs0;
    const f16* gB = W   + (size_t)(n0 + l16) * 768 + quad * 8 + gofs0;
    auto gp = [&](int mat, int kt, int half) {
        return (mat ? gB : gA) + half * HOFF + kt * 64;
    };
    auto lp = [&](int kt, int mat, int half) {
        return &S[(kt & 1) * 32768 + mat * 16384 + half * 4096 + lofs0];
    };

    f32x4 acc[8][4] = {};
    u32x4 sA0a, sA0b, sA1a, sA1b, sB0a, sB0b, sB1a, sB1b;

    // prologue: A(0) h0/h1, B(0) h0/h1, B(1) h0/h1 -> regs -> LDS
    {
        u32x4 p0a, p0b, p1a, p1b, p2a, p2b, p3a, p3b, p4a, p4b, p5a, p5b;
        LD2(p0a, p0b, gp(0, 0, 0)); LD2(p1a, p1b, gp(0, 0, 1));
        LD2(p2a, p2b, gp(1, 0, 0)); LD2(p3a, p3b, gp(1, 0, 1));
        LD2(p4a, p4b, gp(1, 1, 0)); LD2(p5a, p5b, gp(1, 1, 1));
        ST2(p0a, p0b, lp(0, 0, 0)); ST2(p1a, p1b, lp(0, 0, 1));
        ST2(p2a, p2b, lp(0, 1, 0)); ST2(p3a, p3b, lp(0, 1, 1));
        ST2(p4a, p4b, lp(1, 1, 0)); ST2(p5a, p5b, lp(1, 1, 1));
        PUB();
        __builtin_amdgcn_s_barrier();
    }

    f16x8 bfr[4][2];
    for (int kt = 0; kt < 12; ++kt) {
        const f16* SA = &S[(kt & 1) * 32768];
        const f16* SB = SA + 16384;
        #pragma unroll
        for (int jj = 0; jj < 4; ++jj) {
            #pragma unroll
            for (int kk2 = 0; kk2 < 2; ++kk2)
                bfr[jj][kk2] = *(const f16x8*)&SB[kk2 * 8192 + (wc * 4 + jj) * 512 + lq];
        }
        QPHASE(0, { if (kt > 0 && kt + 1 < 12) ST2(sB0a, sB0b, lp(kt + 1, 1, 0)); },
                  { if (kt + 1 < 12) LD2(sA0a, sA0b, gp(0, kt + 1, 0)); });
        QPHASE(2, { if (kt > 0 && kt + 1 < 12) ST2(sB1a, sB1b, lp(kt + 1, 1, 1)); },
                  { if (kt + 1 < 12) LD2(sA1a, sA1b, gp(0, kt + 1, 1)); });
        QPHASE(4, { if (kt + 1 < 12) ST2(sA0a, sA0b, lp(kt + 1, 0, 0)); },
                  { if (kt + 2 < 12) LD2(sB0a, sB0b, gp(1, kt + 2, 0)); });
        QPHASE(6, { if (kt + 1 < 12) ST2(sA1a, sA1b, lp(kt + 1, 0, 1)); },
                  { if (kt + 2 < 12) LD2(sB1a, sB1b, gp(1, kt + 2, 1)); });
    }

    if (z < 2) {
        f16* out = z ? k16 : q16;
        #pragma unroll
        for (int jj = 0; jj < 4; ++jj) {
            int col = n0 + wc * 64 + jj * 16 + l16;
            float bb = bias[col];
            #pragma unroll
            for (int fi = 0; fi < 8; ++fi) {
                #pragma unroll
                for (int r = 0; r < 4; ++r) {
                    int row = m0 + wr * 128 + fi * 16 + quad * 4 + r;
                    out[(size_t)row * 768 + col] = (f16)(acc[fi][jj][r] + bb);
                }
            }
        }
    } else {
        __bf16* Tb = (__bf16*)S;
        const int halfw = wc >> 1;
        const int bofs = (m0 >> 10) * 768;
        const int s0 = m0 & 1023;
        #pragma unroll
        for (int half = 0; half < 2; ++half) {
            __syncthreads();
            if (halfw == half) {
                #pragma unroll
                for (int jj = 0; jj < 4; ++jj) {
                    int el = (wc & 1) * 64 + jj * 16 + l16;
                    float bb = bias[n0 + half * 128 + el];
                    #pragma unroll
                    for (int fi = 0; fi < 8; ++fi) {
                        #pragma unroll
                        for (int r = 0; r < 4; ++r) {
                            int sl = wr * 128 + fi * 16 + quad * 4 + r;
                            Tb[el * LDT2 + sl] = (__bf16)(acc[fi][jj][r] + bb);
                        }
                    }
                }
            }
            __syncthreads();
            const int ch = (t & 31) * 8;
            const int rbase = t >> 5;          // [0,16)
            #pragma unroll
            for (int p = 0; p < 8; ++p) {
                int e = rbase + p * 16;
                bfx8 val = *(const bfx8*)&Tb[e * LDT2 + ch];
                *(bfx8*)&vT[(size_t)(bofs + n0 + half * 128 + e) * 1024 + s0 + ch] = val;
            }
        }
    }
}

// ---------------- K2: p_u = exp(q@k^T + mask), 256x256 causal 8-phase -------
// grid 320 = 8 xcd * (4 batch-groups * 10 causal tiles); K=768 (12 steps).
__global__ __launch_bounds__(512, 2) void logits_kernel(
    const f16* __restrict__ q16, const f16* __restrict__ k16,
    const float* __restrict__ amask, __bf16* __restrict__ pu, float* __restrict__ psum)
{
    const int f = blockIdx.x;
    const int xcd = f & 7;
    const int j = f >> 3;
    const int b = xcd + 8 * (j / 10);
    const int tile = j % 10;
    int mt, nt;
    if (tile < 4)      { mt = 3; nt = tile; }
    else if (tile < 7) { mt = 2; nt = tile - 4; }
    else if (tile < 9) { mt = 1; nt = tile - 7; }
    else               { mt = 0; nt = 0; }
    const int m0 = mt * 256, n0 = nt * 256;
    const size_t pb = (size_t)b << 20;
    const size_t qb = (size_t)b * 1024 * 768;

    __shared__ alignas(16) f16 S[65536];  // 128 KB
    __shared__ float rs[4][256];

    const int t = threadIdx.x, lane = t & 63, wave = t >> 6;
    const int wr = wave >> 2, wc = wave & 3;
    const int wr8 = wr * 8;
    const int quad = lane >> 4, l16 = lane & 15;
    const int lq = quad * 128 + l16 * 8;

    enum { GO1B = 16 * 768 * 2, HOFF = 128 * 768 };
    const int c0 = (wave * 2) & 7, kk0 = wave >> 2;
    const int gofs0 = c0 * 16 * 768 + kk0 * 32;
    const int lofs0 = kk0 * 8192 + c0 * 512 + lane * 8;

    const f16* gA = q16 + qb + (size_t)(m0 + l16) * 768 + quad * 8 + gofs0;
    const f16* gB = k16 + qb + (size_t)(n0 + l16) * 768 + quad * 8 + gofs0;
    auto gp = [&](int mat, int kt, int half) {
        return (mat ? gB : gA) + half * HOFF + kt * 64;
    };
    auto lp = [&](int kt, int mat, int half) {
        return &S[(kt & 1) * 32768 + mat * 16384 + half * 4096 + lofs0];
    };

    f32x4 acc[8][4] = {};
    u32x4 sA0a, sA0b, sA1a, sA1b, sB0a, sB0b, sB1a, sB1b;

    {
        u32x4 p0a, p0b, p1a, p1b, p2a, p2b, p3a, p3b, p4a, p4b, p5a, p5b;
        LD2(p0a, p0b, gp(0, 0, 0)); LD2(p1a, p1b, gp(0, 0, 1));
        LD2(p2a, p2b, gp(1, 0, 0)); LD2(p3a, p3b, gp(1, 0, 1));
        LD2(p4a, p4b, gp(1, 1, 0)); LD2(p5a, p5b, gp(1, 1, 1));
        ST2(p0a, p0b, lp(0, 0, 0)); ST2(p1a, p1b, lp(0, 0, 1));
        ST2(p2a, p2b, lp(0, 1, 0)); ST2(p3a, p3b, lp(0, 1, 1));
        ST2(p4a, p4b, lp(1, 1, 0)); ST2(p5a, p5b, lp(1, 1, 1));
        PUB();
        __builtin_amdgcn_s_barrier();
    }

    f16x8 bfr[4][2];
    for (int kt = 0; kt < 12; ++kt) {
        const f16* SA = &S[(kt & 1) * 32768];
        const f16* SB = SA + 16384;
        #pragma unroll
        for (int jj = 0; jj < 4; ++jj) {
            #pragma unroll
            for (int kk2 = 0; kk2 < 2; ++kk2)
                bfr[jj][kk2] = *(const f16x8*)&SB[kk2 * 8192 + (wc * 4 + jj) * 512 + lq];
        }
        QPHASE(0, { if (kt > 0 && kt + 1 < 12) ST2(sB0a, sB0b, lp(kt + 1, 1, 0)); },
                  { if (kt + 1 < 12) LD2(sA0a, sA0b, gp(0, kt + 1, 0)); });
        QPHASE(2, { if (kt > 0 && kt + 1 < 12) ST2(sB1a, sB1b, lp(kt + 1, 1, 1)); },
                  { if (kt + 1 < 12) LD2(sA1a, sA1b, gp(0, kt + 1, 1)); });
        QPHASE(4, { if (kt + 1 < 12) ST2(sA0a, sA0b, lp(kt + 1, 0, 0)); },
                  { if (kt + 2 < 12) LD2(sB0a, sB0b, gp(1, kt + 2, 0)); });
        QPHASE(6, { if (kt + 1 < 12) ST2(sA1a, sA1b, lp(kt + 1, 0, 1)); },
                  { if (kt + 2 < 12) LD2(sB1a, sB1b, gp(1, kt + 2, 1)); });
    }

    float rp[8][4] = {};
    #pragma unroll
    for (int jj = 0; jj < 4; ++jj) {
        int col = n0 + wc * 64 + jj * 16 + l16;
        float am = (1.0f - amask[b * 1024 + col]) * -10000.0f;
        #pragma unroll
        for (int fi = 0; fi < 8; ++fi) {
            #pragma unroll
            for (int r = 0; r < 4; ++r) {
                int row = m0 + wr * 128 + fi * 16 + quad * 4 + r;
                float s = acc[fi][jj][r] + am;
                float pval = (col <= row) ? __expf(fminf(s, 80.0f)) : 0.0f;
                pu[pb + (size_t)row * 1024 + col] = (__bf16)pval;
                rp[fi][r] += pval;
            }
        }
    }
    #pragma unroll
    for (int fi = 0; fi < 8; ++fi) {
        #pragma unroll
        for (int r = 0; r < 4; ++r) {
            float v = rp[fi][r];
            v += __shfl_xor(v, 1, 64);
            v += __shfl_xor(v, 2, 64);
            v += __shfl_xor(v, 4, 64);
            v += __shfl_xor(v, 8, 64);   // sum over l16 group
            if (l16 == 0) rs[wc][wr * 128 + fi * 16 + quad * 4 + r] = v;
        }
    }
    __syncthreads();
    if (t < 256)
        psum[((size_t)b * 1024 + m0 + t) * 4 + nt] =
            rs[0][t] + rs[1][t] + rs[2][t] + rs[3][t];
}

// ---------------- K3: h = (p_u @ v) / rowsum, 256x256 8-phase ---------------
// grid 384 = 8 xcd * (4 batch-groups * 12 tiles), longest K (mt=3) first.
// Runtime K: nkt = 4*(mt+1) BK=64 steps (p_u zero above diagonal).
__global__ __launch_bounds__(512, 2) void pv_kernel(
    const __bf16* __restrict__ pu, const __bf16* __restrict__ vT,
    const float* __restrict__ psum, __bf16* __restrict__ h)
{
    const int f = blockIdx.x;
    const int xcd = f & 7;
    const int j = f >> 3;
    const int b = xcd + 8 * (j / 12);
    const int tile = j % 12;
    const int mt = 3 - tile / 3, nt = tile % 3;
    const int m0 = mt * 256, n0 = nt * 256;
    const int nkt = 4 * (mt + 1);
    const size_t pb = (size_t)b << 20;
    const size_t vb = (size_t)b * 768 * 1024;

    __shared__ alignas(16) __bf16 S[65536];  // 128 KB
    __shared__ float invl[256];

    const int t = threadIdx.x, lane = t & 63, wave = t >> 6;
    const int wr = wave >> 2, wc = wave & 3;
    const int wr8 = wr * 8;
    const int quad = lane >> 4, l16 = lane & 15;
    const int lq = quad * 128 + l16 * 8;

    if (t < 256) {
        int row = m0 + t;
        int lim = row >> 8;  // psum[row][n] written only for n <= row>>8
        const float* pr = &psum[((size_t)b * 1024 + row) * 4];
        float s = 0.f;
        #pragma unroll
        for (int n = 0; n < 4; ++n) s += (n <= lim) ? pr[n] : 0.f;
        invl[t] = 1.0f / s;
    }

    enum { GO1B = 16 * 1024 * 2, HOFF = 128 * 1024 };
    const int c0 = (wave * 2) & 7, kk0 = wave >> 2;
    const int gofs0 = c0 * 16 * 1024 + kk0 * 32;
    const int lofs0 = kk0 * 8192 + c0 * 512 + lane * 8;

    const __bf16* gA = pu + pb + (size_t)(m0 + l16) * 1024 + quad * 8 + gofs0;
    const __bf16* gB = vT + vb + (size_t)(n0 + l16) * 1024 + quad * 8 + gofs0;
    auto gp = [&](int mat, int kt, int half) {
        return (mat ? gB : gA) + half * HOFF + kt * 64;
    };
    auto lp = [&](int kt, int mat, int half) {
        return &S[(kt & 1) * 32768 + mat * 16384 + half * 4096 + lofs0];
    };

    f32x4 acc[8][4] = {};
    u32x4 sA0a, sA0b, sA1a, sA1b, sB0a, sB0b, sB1a, sB1b;

    {
        u32x4 p0a, p0b, p1a, p1b, p2a, p2b, p3a, p3b, p4a, p4b, p5a, p5b;
        LD2(p0a, p0b, gp(0, 0, 0)); LD2(p1a, p1b, gp(0, 0, 1));
        LD2(p2a, p2b, gp(1, 0, 0)); LD2(p3a, p3b, gp(1, 0, 1));
        LD2(p4a, p4b, gp(1, 1, 0)); LD2(p5a, p5b, gp(1, 1, 1));
        ST2(p0a, p0b, lp(0, 0, 0)); ST2(p1a, p1b, lp(0, 0, 1));
        ST2(p2a, p2b, lp(0, 1, 0)); ST2(p3a, p3b, lp(0, 1, 1));
        ST2(p4a, p4b, lp(1, 1, 0)); ST2(p5a, p5b, lp(1, 1, 1));
        PUB();
        __builtin_amdgcn_s_barrier();
    }

    bfx8 bfr[4][2];
    for (int kt = 0; kt < nkt; ++kt) {
        const __bf16* SA = &S[(kt & 1) * 32768];
        const __bf16* SB = SA + 16384;
        #pragma unroll
        for (int jj = 0; jj < 4; ++jj) {
            #pragma unroll
            for (int kk2 = 0; kk2 < 2; ++kk2)
                bfr[jj][kk2] = *(const bfx8*)&SB[kk2 * 8192 + (wc * 4 + jj) * 512 + lq];
        }
        QPHASE_BF(0, { if (kt > 0 && kt + 1 < nkt) ST2(sB0a, sB0b, lp(kt + 1, 1, 0)); },
                     { if (kt + 1 < nkt) LD2(sA0a, sA0b, gp(0, kt + 1, 0)); });
        QPHASE_BF(2, { if (kt > 0 && kt + 1 < nkt) ST2(sB1a, sB1b, lp(kt + 1, 1, 1)); },
                     { if (kt + 1 < nkt) LD2(sA1a, sA1b, gp(0, kt + 1, 1)); });
        QPHASE_BF(4, { if (kt + 1 < nkt) ST2(sA0a, sA0b, lp(kt + 1, 0, 0)); },
                     { if (kt + 2 < nkt) LD2(sB0a, sB0b, gp(1, kt + 2, 0)); });
        QPHASE_BF(6, { if (kt + 1 < nkt) ST2(sA1a, sA1b, lp(kt + 1, 0, 1)); },
                     { if (kt + 2 < nkt) LD2(sB1a, sB1b, gp(1, kt + 2, 1)); });
    }

    #pragma unroll
    for (int jj = 0; jj < 4; ++jj) {
        int col = n0 + wc * 64 + jj * 16 + l16;
        #pragma unroll
        for (int fi = 0; fi < 8; ++fi) {
            #pragma unroll
            for (int r = 0; r < 4; ++r) {
                int rl = wr * 128 + fi * 16 + quad * 4 + r;
                h[((size_t)b * 1024 + m0 + rl) * 768 + col] = (__bf16)(acc[fi][jj][r] * invl[rl]);
            }
        }
    }
}

// ---------------- K4: out = relu(h @ W1^T + b1) @ W2^T + b2 -----------------
__global__ __launch_bounds__(256) void mlp_kernel(
    const __bf16* __restrict__ h, const float* __restrict__ W1, const float* __restrict__ b1,
    const float* __restrict__ W2, const float* __restrict__ b2, float* __restrict__ out)
{
    const int wave = threadIdx.x >> 6, lane = threadIdx.x & 63;
    const int quad = lane >> 4, l16 = lane & 15;
    const int m0 = blockIdx.x * 64 + wave * 16;

    f32x4 acc[4] = {};
    for (int k0 = 0; k0 < 768; k0 += 32) {
        bfx8 af = *(const bfx8*)&h[(size_t)(m0 + l16) * 768 + k0 + quad * 8];
        #pragma unroll
        for (int jj = 0; jj < 4; ++jj) {
            const float* wp = W1 + (size_t)(jj * 16 + l16) * 768 + k0 + quad * 8;
            f32x4 w0 = *(const f32x4*)wp;
            f32x4 w1 = *(const f32x4*)(wp + 4);
            bfx8 bg;
            #pragma unroll
            for (int e = 0; e < 4; ++e) { bg[e] = (__bf16)w0[e]; bg[e + 4] = (__bf16)w1[e]; }
            acc[jj] = MFMA_BF16(af, bg, acc[jj]);
        }
    }
    float part[4][2] = {};
    #pragma unroll
    for (int jj = 0; jj < 4; ++jj) {
        int c = jj * 16 + l16;
        float bb = b1[c];
        float w20 = W2[c], w21 = W2[64 + c];
        #pragma unroll
        for (int r = 0; r < 4; ++r) {
            float x = fmaxf(acc[jj][r] + bb, 0.f);
            part[r][0] += x * w20;
            part[r][1] += x * w21;
        }
    }
    #pragma unroll
    for (int off = 1; off < 16; off <<= 1)
        #pragma unroll
        for (int r = 0; r < 4; ++r) {
            part[r][0] += __shfl_xor(part[r][0], off, 64);
            part[r][1] += __shfl_xor(part[r][1], off, 64);
        }
    if (l16 == 0) {
        #pragma unroll
        for (int r = 0; r < 4; ++r) {
            int row = m0 + quad * 4 + r;
            out[(size_t)row * 2 + 0] = part[r][0] + b2[0];
            out[(size_t)row * 2 + 1] = part[r][1] + b2[1];
        }
    }
}

// ---------------------------------------------------------------------------
extern "C" void kernel_launch(void* const* d_in, const int* in_sizes, int n_in,
                              void* d_out, int out_size, void* d_ws, size_t ws_size,
                              hipStream_t stream)
{
    const float* hidden = (const float*)d_in[0];
    const float* amask  = (const float*)d_in[1];
    const float* Wk = (const float*)d_in[2];
    const float* bk = (const float*)d_in[3];
    const float* Wq = (const float*)d_in[4];
    const float* bq = (const float*)d_in[5];
    const float* Wv = (const float*)d_in[6];
    const float* bv = (const float*)d_in[7];
    const float* W1 = (const float*)d_in[8];
    const float* b1 = (const float*)d_in[9];
    const float* W2 = (const float*)d_in[10];
    const float* b2 = (const float*)d_in[11];
    float* out = (float*)d_out;

    char* ws = (char*)d_ws;
    const size_t MB = 1024 * 1024;
    f16* h16 = (f16*)ws;
    f16* wq16 = (f16*)(ws + 48 * MB);
    f16* wk16 = wq16 + 589824;
    f16* wv16 = wk16 + 589824;
    __bf16* pu  = (__bf16*)ws;                 // aliases h16/W16 (dead after qkv)
    float*  psum = (float*)(ws + 64 * MB);     // 32*1024*4 fp32 = 512 KB
    f16* q16 = (f16*)(ws + 66 * MB);
    f16* k16 = (f16*)(ws + 114 * MB);
    __bf16* vT = (__bf16*)(ws + 162 * MB);
    __bf16* h  = (__bf16*)(ws + 66 * MB);      // aliases q16 (dead after logits)
    const size_t NEED = 210 * MB;
    if (ws_size < NEED) {
        fprintf(stderr, "[Attn kernel] ws too small: %zu < %zu — skipping launches\n",
                ws_size, NEED);
        return;
    }

    cvt_all<<<24576 + 1728, 256, 0, stream>>>(
        hidden, Wq, Wk, Wv, h16, wq16, wk16, wv16);

    qkv_kernel<<<1152, 512, 0, stream>>>(
        h16, wq16, wk16, wv16, bq, bk, bv, q16, k16, vT);
    logits_kernel<<<320, 512, 0, stream>>>(q16, k16, amask, pu, psum);
    pv_kernel<<<384, 512, 0, stream>>>(pu, vT, psum, h);
    mlp_kernel<<<512, 256, 0, stream>>>(h, W1, b1, W2, b2, out);
}

// Round 6
// 492.479 us; speedup vs baseline: 1.0755x; 1.0755x over previous
//
#include <hip/hip_runtime.h>
#include <hip/hip_bf16.h>
#include <cstdio>

// ---------------------------------------------------------------------------
// Attn_59940563583594: hidden[32,1024,768] -> QKV -> causal attn (no 1/sqrt(d))
//                      -> relu MLP(768->64) -> out[32,1024,2] fp32
// Numerics (verified R2-R8: absmax 9.8e-4 vs 3.8e-3 threshold):
//   f16 storage/MFMA for hidden/W/q/k, no-max softmax (exp clamp 80,
//   unnormalized bf16 p, fp32 row sums, normalize in PV), bf16 PV + MLP.
// R11-R14: four schedule variants (2ph/8ph/clobber-free/reg-staged) all at
//   610-680 TF -> the 8-phase lever doesn't reproduce at K=12 + 4.5-round
//   grids. R15: per-kernel best-measured reversion + additive wins:
//   - qkv: R13 form (256^2 8ph gl_lds, 171 us best).
//   - logits/pv: R10 forms (128^2 2ph, 4 blocks/CU, grids 1152/1536 ->
//     fine makespan quantization; R10 A/B showed -13 us vs 256^2 forms).
//   - mlp: W1 pre-converted to bf16 in cvt_all (halves W1 traffic,
//     removes per-iter cvt VALU).
// ---------------------------------------------------------------------------

typedef _Float16 f16;
typedef f16    f16x8 __attribute__((ext_vector_type(8)));
typedef f16    f16x4 __attribute__((ext_vector_type(4)));
typedef __bf16 bfx8  __attribute__((ext_vector_type(8)));
typedef __bf16 bfx4  __attribute__((ext_vector_type(4)));
typedef float  f32x4 __attribute__((ext_vector_type(4)));

#define MFMA_F16(a,b,c)  __builtin_amdgcn_mfma_f32_16x16x32_f16((a),(b),(c),0,0,0)
#define MFMA_BF16(a,b,c) __builtin_amdgcn_mfma_f32_16x16x32_bf16((a),(b),(c),0,0,0)

static constexpr int LDT2 = 264;  // qkv v-transpose stride (128e x 256s)

__device__ __forceinline__ void gl_lds16(const void* g, void* l) {
    __builtin_amdgcn_global_load_lds(
        (const __attribute__((address_space(1))) void*)g,
        (__attribute__((address_space(3))) void*)l, 16, 0, 0);
}

// clobber-free waits, pinned with sched_barrier(0) (rule #18 / m201 pattern)
#define WAIT_VMCNT(n)                                        \
    do { asm volatile("s_waitcnt vmcnt(" #n ")");            \
         __builtin_amdgcn_sched_barrier(0); } while (0)
#define WAIT_LGKM0()                                         \
    do { asm volatile("s_waitcnt lgkmcnt(0)");               \
         __builtin_amdgcn_sched_barrier(0); } while (0)

// ---------------- fp32 -> f16/bf16 convert (hidden + 4 weights) -------------
__global__ __launch_bounds__(256) void cvt_all(
    const float* __restrict__ hidden,
    const float* __restrict__ Wq, const float* __restrict__ Wk, const float* __restrict__ Wv,
    const float* __restrict__ W1,
    f16* __restrict__ h16, f16* __restrict__ oq, f16* __restrict__ ok, f16* __restrict__ ov,
    __bf16* __restrict__ w1b)
{
    const int bid = blockIdx.x;
    if (bid >= 26304) {                      // W1 -> bf16 (48 blocks)
        int base = ((bid - 26304) * 256 + threadIdx.x) * 4;
        f32x4 v = *(const f32x4*)(W1 + base);
        bfx4 o;
        #pragma unroll
        for (int e = 0; e < 4; ++e) o[e] = (__bf16)v[e];
        *(bfx4*)(w1b + base) = o;
        return;
    }
    const float* src;
    f16* dst;
    int base;
    if (bid < 24576) {
        src = hidden; dst = h16;
        base = (bid * 256 + threadIdx.x) * 4;
    } else {
        int wz = (bid - 24576) / 576, wb = (bid - 24576) % 576;
        src = (wz == 0) ? Wq : (wz == 1) ? Wk : Wv;
        dst = (wz == 0) ? oq : (wz == 1) ? ok : ov;
        base = (wb * 256 + threadIdx.x) * 4;
    }
    f32x4 v = *(const f32x4*)(src + base);
    f16x4 o;
    #pragma unroll
    for (int e = 0; e < 4; ++e) o[e] = (f16)v[e];
    *(f16x4*)(dst + base) = o;
}

// ---- 8-phase QPHASE (qkv only): {ds_read A | stage | gate | barrier | lgkm0
//                                  | 16 MFMA | barrier}
#define QPHASE(fr0, STAGE_STMT, GATE_STMT)                                        \
    {                                                                             \
        f16x8 afr[2][2];                                                          \
        _Pragma("unroll")                                                         \
        for (int i = 0; i < 2; ++i) {                                             \
            _Pragma("unroll")                                                     \
            for (int kk = 0; kk < 2; ++kk)                                        \
                afr[i][kk] = *(const f16x8*)&SA[kk * 8192 + (wr8 + (fr0) + i) * 512 + lq]; \
        }                                                                         \
        STAGE_STMT;                                                               \
        GATE_STMT;                                                                \
        __builtin_amdgcn_s_barrier();                                             \
        WAIT_LGKM0();                                                             \
        __builtin_amdgcn_s_setprio(1);                                            \
        _Pragma("unroll")                                                         \
        for (int i = 0; i < 2; ++i) {                                             \
            _Pragma("unroll")                                                     \
            for (int jj = 0; jj < 4; ++jj) {                                      \
                acc[(fr0) + i][jj] = MFMA_F16(afr[i][0], bfr[jj][0], acc[(fr0) + i][jj]); \
                acc[(fr0) + i][jj] = MFMA_F16(afr[i][1], bfr[jj][1], acc[(fr0) + i][jj]); \
            }                                                                     \
        }                                                                         \
        __builtin_amdgcn_s_setprio(0);                                            \
        __builtin_amdgcn_s_barrier();                                             \
    }

// ---------------- K1: fused q,k,v projections, 256x256 8-phase (R13) --------
// grid 1152 = 8 xcd * (3 nt * 3 z * 16 mi); mt = xcd + 8*mi; 512 threads.
__global__ __launch_bounds__(512, 2) void qkv_kernel(
    const f16* __restrict__ h16,
    const f16* __restrict__ wq, const f16* __restrict__ wk, const f16* __restrict__ wv,
    const float* __restrict__ bq, const float* __restrict__ bk, const float* __restrict__ bv,
    f16* __restrict__ q16, f16* __restrict__ k16, __bf16* __restrict__ vT)
{
    const int f = blockIdx.x;
    const int xcd = f & 7;
    const int j = f >> 3;
    const int nt = j % 3;
    const int z  = (j / 3) % 3;
    const int mi = j / 9;                 // [0,16)
    const int mt = xcd + 8 * mi;          // [0,128)
    const int m0 = mt * 256, n0 = nt * 256;

    const f16* W = (z == 0) ? wq : (z == 1) ? wk : wv;
    const float* bias = (z == 0) ? bq : (z == 1) ? bk : bv;

    __shared__ alignas(16) f16 S[65536];  // 128 KB

    const int t = threadIdx.x, lane = t & 63, wave = t >> 6;
    const int wr = wave >> 2, wc = wave & 3;      // 2M x 4N wave grid
    const int wr8 = wr * 8;
    const int quad = lane >> 4, l16 = lane & 15;
    const int lq = quad * 128 + l16 * 8;

    const f16* gA = h16 + (size_t)(m0 + l16) * 768 + quad * 8;
    const f16* gB = W   + (size_t)(n0 + l16) * 768 + quad * 8;
    int gofs[2], lofs[2];
    #pragma unroll
    for (int u = 0; u < 2; ++u) {
        int unit = wave * 2 + u;
        int kk = unit >> 3, c = unit & 7;
        gofs[u] = c * 16 * 768 + kk * 32;
        lofs[u] = kk * 8192 + c * 512;
    }
    auto stage = [&](int kt, int mat, int half) {
        const f16* gp = (mat ? gB : gA) + half * (128 * 768) + kt * 64;
        f16* lp = &S[(kt & 1) * 32768 + mat * 16384 + half * 4096];
        gl_lds16(gp + gofs[0], lp + lofs[0]);
        gl_lds16(gp + gofs[1], lp + lofs[1]);
    };

    f32x4 acc[8][4] = {};

    stage(0, 0, 0); stage(0, 0, 1); stage(0, 1, 0); stage(0, 1, 1);
    stage(1, 1, 0); stage(1, 1, 1);
    WAIT_VMCNT(4);   // kt0 landed
    __builtin_amdgcn_s_barrier();

    f16x8 bfr[4][2];
    for (int kt = 0; kt < 12; ++kt) {
        const f16* SA = &S[(kt & 1) * 32768];
        const f16* SB = SA + 16384;
        #pragma unroll
        for (int jj = 0; jj < 4; ++jj) {
            #pragma unroll
            for (int kk = 0; kk < 2; ++kk)
                bfr[jj][kk] = *(const f16x8*)&SB[kk * 8192 + (wc * 4 + jj) * 512 + lq];
        }
        QPHASE(0, { if (kt + 1 < 12) stage(kt + 1, 0, 0); }, {});
        QPHASE(2, { if (kt + 1 < 12) stage(kt + 1, 0, 1); }, {});
        QPHASE(4, { if (kt + 2 < 12) stage(kt + 2, 1, 0); }, {});
        QPHASE(6, { if (kt + 2 < 12) stage(kt + 2, 1, 1); },
               {
                   if (kt + 2 < 12)       WAIT_VMCNT(4);
                   else if (kt + 1 < 12)  WAIT_VMCNT(0);
               });
    }

    if (z < 2) {
        f16* out = z ? k16 : q16;
        #pragma unroll
        for (int jj = 0; jj < 4; ++jj) {
            int col = n0 + wc * 64 + jj * 16 + l16;
            float bb = bias[col];
            #pragma unroll
            for (int fi = 0; fi < 8; ++fi) {
                #pragma unroll
                for (int r = 0; r < 4; ++r) {
                    int row = m0 + wr * 128 + fi * 16 + quad * 4 + r;
                    out[(size_t)row * 768 + col] = (f16)(acc[fi][jj][r] + bb);
                }
            }
        }
    } else {
        __bf16* Tb = (__bf16*)S;
        const int halfw = wc >> 1;
        const int bofs = (m0 >> 10) * 768;
        const int s0 = m0 & 1023;
        #pragma unroll
        for (int half = 0; half < 2; ++half) {
            __syncthreads();
            if (halfw == half) {
                #pragma unroll
                for (int jj = 0; jj < 4; ++jj) {
                    int el = (wc & 1) * 64 + jj * 16 + l16;
                    float bb = bias[n0 + half * 128 + el];
                    #pragma unroll
                    for (int fi = 0; fi < 8; ++fi) {
                        #pragma unroll
                        for (int r = 0; r < 4; ++r) {
                            int sl = wr * 128 + fi * 16 + quad * 4 + r;
                            Tb[el * LDT2 + sl] = (__bf16)(acc[fi][jj][r] + bb);
                        }
                    }
                }
            }
            __syncthreads();
            const int ch = (t & 31) * 8;
            const int rbase = t >> 5;          // [0,16)
            #pragma unroll
            for (int p = 0; p < 8; ++p) {
                int e = rbase + p * 16;
                bfx8 val = *(const bfx8*)&Tb[e * LDT2 + ch];
                *(bfx8*)&vT[(size_t)(bofs + n0 + half * 128 + e) * 1024 + s0 + ch] = val;
            }
        }
    }
}

// ---------------- K2: p_u = exp(q@k^T + mask), 128x128 causal tiles (R10) ---
// grid 1152 = 8 xcd * (4 batch-groups * 36 causal tiles); K=768 uniform.
__global__ __launch_bounds__(256, 4) void logits_kernel(
    const f16* __restrict__ q16, const f16* __restrict__ k16,
    const float* __restrict__ amask, __bf16* __restrict__ pu, float* __restrict__ psum)
{
    const int f = blockIdx.x;
    const int xcd = f & 7;
    const int j = f >> 3;
    const int b = xcd + 8 * (j / 36);
    const int tile = j % 36;
    int mt = 0, base = 0;
    while (base + mt + 1 <= tile) { base += mt + 1; ++mt; }
    const int nt = tile - base;                 // nt <= mt (causal)
    const int m0 = mt * 128, n0 = nt * 128;
    const size_t pb = (size_t)b << 20;
    const size_t qb = (size_t)b * 1024 * 768;

    __shared__ alignas(16) f16 S[2][8192];      // 32 KB dbuf
    __shared__ float rs[2][128];

    const int t = threadIdx.x, lane = t & 63, wave = t >> 6;
    const int wm = (wave & 1) * 64, wn = (wave >> 1) * 64;
    const int quad = lane >> 4, l16 = lane & 15;

    const f16* gsrc[4];
    int ldst[4];
    #pragma unroll
    for (int u = 0; u < 4; ++u) {
        int c = wave * 4 + u;
        ldst[u] = c * 512;
        const f16* base2 = (c < 8) ? (q16 + qb + (size_t)(m0 + c * 16 + l16) * 768)
                                   : (k16 + qb + (size_t)(n0 + (c - 8) * 16 + l16) * 768);
        gsrc[u] = base2 + quad * 8;
    }

    f32x4 acc[4][4] = {};
    auto stage = [&](int k0, int buf) {
        #pragma unroll
        for (int u = 0; u < 4; ++u)
            gl_lds16(gsrc[u] + k0, &S[buf][ldst[u]]);
    };
    auto compute = [&](int buf) {
        f16x8 af[4], bg[4];
        #pragma unroll
        for (int i = 0; i < 4; ++i) {
            af[i] = *(const f16x8*)&S[buf][(wm / 16 + i) * 512 + quad * 128 + l16 * 8];
            bg[i] = *(const f16x8*)&S[buf][(8 + wn / 16 + i) * 512 + quad * 128 + l16 * 8];
        }
        #pragma unroll
        for (int i = 0; i < 4; ++i)
            #pragma unroll
            for (int jj = 0; jj < 4; ++jj)
                acc[i][jj] = MFMA_F16(af[i], bg[jj], acc[i][jj]);
    };

    stage(0, 0);
    int cur = 0;
    for (int k0 = 32; k0 < 768; k0 += 32) {
        __syncthreads();
        stage(k0, cur ^ 1);
        compute(cur);
        cur ^= 1;
    }
    __syncthreads();
    compute(cur);

    float rp[4][4] = {};
    #pragma unroll
    for (int jj = 0; jj < 4; ++jj) {
        int col = n0 + wn + jj * 16 + l16;
        float am = (1.0f - amask[b * 1024 + col]) * -10000.0f;
        #pragma unroll
        for (int i = 0; i < 4; ++i)
            #pragma unroll
            for (int r = 0; r < 4; ++r) {
                int row = m0 + wm + i * 16 + quad * 4 + r;
                float s = acc[i][jj][r] + am;
                float pval = (col <= row) ? __expf(fminf(s, 80.0f)) : 0.0f;
                pu[pb + (size_t)row * 1024 + col] = (__bf16)pval;
                rp[i][r] += pval;
            }
    }
    #pragma unroll
    for (int i = 0; i < 4; ++i)
        #pragma unroll
        for (int r = 0; r < 4; ++r) {
            float v = rp[i][r];
            v += __shfl_xor(v, 1, 64);
            v += __shfl_xor(v, 2, 64);
            v += __shfl_xor(v, 4, 64);
            v += __shfl_xor(v, 8, 64);   // sum over l16 group
            if (l16 == 0) rs[wn >> 6][wm + i * 16 + quad * 4 + r] = v;
        }
    __syncthreads();
    if (t < 128)
        psum[((size_t)b * 1024 + m0 + t) * 8 + nt] = rs[0][t] + rs[1][t];
}

// ---------------- K3: h = (p_u @ v) / rowsum, 128x128 tiles (R10) -----------
// grid 1536 = 8 xcd * (4 batch-groups * 48 tiles), longest K (mt=7) first.
__global__ __launch_bounds__(256, 4) void pv_kernel(
    const __bf16* __restrict__ pu, const __bf16* __restrict__ vT,
    const float* __restrict__ psum, __bf16* __restrict__ h)
{
    const int f = blockIdx.x;
    const int xcd = f & 7;
    const int j = f >> 3;
    const int b = xcd + 8 * (j / 48);
    const int tile = j % 48;
    const int mt = 7 - tile / 6, nt = tile % 6;
    const int m0 = mt * 128, n0 = nt * 128;
    const size_t pb = (size_t)b << 20;
    const size_t vb = (size_t)b * 768 * 1024;

    __shared__ alignas(16) __bf16 S[2][8192];   // 32 KB dbuf
    __shared__ float invl[128];

    const int t = threadIdx.x, lane = t & 63, wave = t >> 6;
    const int wm = (wave & 1) * 64, wn = (wave >> 1) * 64;
    const int quad = lane >> 4, l16 = lane & 15;

    if (t < 128) {
        int row = m0 + t;
        int lim = row >> 7;  // psum[row][n] written only for n <= row>>7
        const float* pr = &psum[((size_t)b * 1024 + row) * 8];
        float s = 0.f;
        #pragma unroll
        for (int n = 0; n < 8; ++n) s += (n <= lim) ? pr[n] : 0.f;
        invl[t] = 1.0f / s;
    }

    const __bf16* gsrc[4];
    int ldst[4];
    #pragma unroll
    for (int u = 0; u < 4; ++u) {
        int c = wave * 4 + u;
        ldst[u] = c * 512;
        const __bf16* base = (c < 8) ? (pu + pb + (size_t)(m0 + c * 16 + l16) * 1024)
                                     : (vT + vb + (size_t)(n0 + (c - 8) * 16 + l16) * 1024);
        gsrc[u] = base + quad * 8;
    }

    f32x4 acc[4][4] = {};
    auto stage = [&](int k0, int buf) {
        #pragma unroll
        for (int u = 0; u < 4; ++u)
            gl_lds16(gsrc[u] + k0, &S[buf][ldst[u]]);
    };
    auto compute = [&](int buf) {
        bfx8 af[4], bg[4];
        #pragma unroll
        for (int i = 0; i < 4; ++i) {
            af[i] = *(const bfx8*)&S[buf][(wm / 16 + i) * 512 + quad * 128 + l16 * 8];
            bg[i] = *(const bfx8*)&S[buf][(8 + wn / 16 + i) * 512 + quad * 128 + l16 * 8];
        }
        #pragma unroll
        for (int i = 0; i < 4; ++i)
            #pragma unroll
            for (int jj = 0; jj < 4; ++jj)
                acc[i][jj] = MFMA_BF16(af[i], bg[jj], acc[i][jj]);
    };

    const int kend = m0 + 128;  // p_u is exactly 0 above the diagonal
    stage(0, 0);
    int cur = 0;
    for (int k0 = 32; k0 < kend; k0 += 32) {
        __syncthreads();
        stage(k0, cur ^ 1);
        compute(cur);
        cur ^= 1;
    }
    __syncthreads();
    compute(cur);

    #pragma unroll
    for (int jj = 0; jj < 4; ++jj) {
        int col = n0 + wn + jj * 16 + l16;
        #pragma unroll
        for (int i = 0; i < 4; ++i)
            #pragma unroll
            for (int r = 0; r < 4; ++r) {
                int rl = wm + i * 16 + quad * 4 + r;
                h[((size_t)b * 1024 + m0 + rl) * 768 + col] = (__bf16)(acc[i][jj][r] * invl[rl]);
            }
    }
}

// ---------------- K4: out = relu(h @ W1b^T + b1) @ W2^T + b2 ----------------
__global__ __launch_bounds__(256) void mlp_kernel(
    const __bf16* __restrict__ h, const __bf16* __restrict__ W1b, const float* __restrict__ b1,
    const float* __restrict__ W2, const float* __restrict__ b2, float* __restrict__ out)
{
    const int wave = threadIdx.x >> 6, lane = threadIdx.x & 63;
    const int quad = lane >> 4, l16 = lane & 15;
    const int m0 = blockIdx.x * 64 + wave * 16;

    f32x4 acc[4] = {};
    for (int k0 = 0; k0 < 768; k0 += 32) {
        bfx8 af = *(const bfx8*)&h[(size_t)(m0 + l16) * 768 + k0 + quad * 8];
        #pragma unroll
        for (int jj = 0; jj < 4; ++jj) {
            bfx8 bg = *(const bfx8*)&W1b[(size_t)(jj * 16 + l16) * 768 + k0 + quad * 8];
            acc[jj] = MFMA_BF16(af, bg, acc[jj]);
        }
    }
    float part[4][2] = {};
    #pragma unroll
    for (int jj = 0; jj < 4; ++jj) {
        int c = jj * 16 + l16;
        float bb = b1[c];
        float w20 = W2[c], w21 = W2[64 + c];
        #pragma unroll
        for (int r = 0; r < 4; ++r) {
            float x = fmaxf(acc[jj][r] + bb, 0.f);
            part[r][0] += x * w20;
            part[r][1] += x * w21;
        }
    }
    #pragma unroll
    for (int off = 1; off < 16; off <<= 1)
        #pragma unroll
        for (int r = 0; r < 4; ++r) {
            part[r][0] += __shfl_xor(part[r][0], off, 64);
            part[r][1] += __shfl_xor(part[r][1], off, 64);
        }
    if (l16 == 0) {
        #pragma unroll
        for (int r = 0; r < 4; ++r) {
            int row = m0 + quad * 4 + r;
            out[(size_t)row * 2 + 0] = part[r][0] + b2[0];
            out[(size_t)row * 2 + 1] = part[r][1] + b2[1];
        }
    }
}

// ---------------------------------------------------------------------------
extern "C" void kernel_launch(void* const* d_in, const int* in_sizes, int n_in,
                              void* d_out, int out_size, void* d_ws, size_t ws_size,
                              hipStream_t stream)
{
    const float* hidden = (const float*)d_in[0];
    const float* amask  = (const float*)d_in[1];
    const float* Wk = (const float*)d_in[2];
    const float* bk = (const float*)d_in[3];
    const float* Wq = (const float*)d_in[4];
    const float* bq = (const float*)d_in[5];
    const float* Wv = (const float*)d_in[6];
    const float* bv = (const float*)d_in[7];
    const float* W1 = (const float*)d_in[8];
    const float* b1 = (const float*)d_in[9];
    const float* W2 = (const float*)d_in[10];
    const float* b2 = (const float*)d_in[11];
    float* out = (float*)d_out;

    char* ws = (char*)d_ws;
    const size_t MB = 1024 * 1024;
    f16* h16 = (f16*)ws;
    f16* wq16 = (f16*)(ws + 48 * MB);
    f16* wk16 = wq16 + 589824;
    f16* wv16 = wk16 + 589824;
    __bf16* pu  = (__bf16*)ws;                 // aliases h16/W16 (dead after qkv)
    float*  psum = (float*)(ws + 64 * MB);     // 32*1024*8 fp32 = 1 MB
    __bf16* w1b = (__bf16*)(ws + 65 * MB);     // 64*768 bf16 = 96 KB
    f16* q16 = (f16*)(ws + 66 * MB);
    f16* k16 = (f16*)(ws + 114 * MB);
    __bf16* vT = (__bf16*)(ws + 162 * MB);
    __bf16* h  = (__bf16*)(ws + 66 * MB);      // aliases q16 (dead after logits)
    const size_t NEED = 210 * MB;
    if (ws_size < NEED) {
        fprintf(stderr, "[Attn kernel] ws too small: %zu < %zu — skipping launches\n",
                ws_size, NEED);
        return;
    }

    cvt_all<<<24576 + 1728 + 48, 256, 0, stream>>>(
        hidden, Wq, Wk, Wv, W1, h16, wq16, wk16, wv16, w1b);

    qkv_kernel<<<1152, 512, 0, stream>>>(
        h16, wq16, wk16, wv16, bq, bk, bv, q16, k16, vT);
    logits_kernel<<<1152, 256, 0, stream>>>(q16, k16, amask, pu, psum);
    pv_kernel<<<1536, 256, 0, stream>>>(pu, vT, psum, h);
    mlp_kernel<<<512, 256, 0, stream>>>(h, w1b, b1, W2, b2, out);
}